// Round 9
// baseline (184.445 us; speedup 1.0000x reference)
//
#include <hip/hip_runtime.h>

typedef _Float16 half8 __attribute__((ext_vector_type(8)));
typedef float f32x4 __attribute__((ext_vector_type(4)));

#define HW 16384
#define FDIM 256
#define DDIM 128

union H8 { half8 v; uint4 q; _Float16 h[8]; };
union H4 { uint2 q; _Float16 h[4]; };

// ---------------- prep: q projection (f32, exact) + MFMA-fragment pre-layout ----------------
__global__ __launch_bounds__(256) void prep_kernel(
    const float* __restrict__ proto, const float* __restrict__ Wk,
    const float* __restrict__ Wq, const float* __restrict__ bq,
    float* __restrict__ protos_out, _Float16* __restrict__ Wkf,
    _Float16* __restrict__ qf)
{
  const int bid = blockIdx.x, t = threadIdx.x;
  if (bid < 96) {
    const int b = bid / 6, c = bid % 6;
    __shared__ float protoS[10 * FDIM];
    const float* pbase = proto + (size_t)((b * 6 + c) * 10) * FDIM;
#pragma unroll
    for (int i = 0; i < 10; ++i) protoS[t + 256 * i] = pbase[t + 256 * i];
    __syncthreads();
#pragma unroll
    for (int i = 0; i < 5; ++i) {
      const int oid = t + 256 * i;               // 1280 outputs: (p, d)
      const int p = oid >> 7, d = oid & 127;
      const float* wq = Wq + (size_t)(c * DDIM + d) * FDIM;
      float acc = bq[c * DDIM + d];
      for (int f = 0; f < FDIM; ++f) acc += wq[f] * protoS[p * FDIM + f];
      protos_out[((b * 6 + c) * 10 + p) * DDIM + d] = acc;
      // qf[b][cpt][ks2][lane][j]: cp = cpt*16 + (l&15), d = ks2*32 + (l>>4)*8 + j
      const int cp = c * 10 + p;
      const int cpt = cp >> 4, lr = cp & 15, ks2 = d >> 5, lg = (d >> 3) & 3, j = d & 7;
      qf[((((b * 4 + cpt) * 4 + ks2) * 64) + lg * 16 + lr) * 8 + j] = (_Float16)acc;
    }
    if (c == 5) {  // zero the cp = 60..63 padding rows for this b
#pragma unroll
      for (int i = 0; i < 2; ++i) {
        const int zid = t + 256 * i;
        const int cp = 60 + (zid >> 7), d = zid & 127;
        const int cpt = cp >> 4, lr = cp & 15, ks2 = d >> 5, lg = (d >> 3) & 3, j = d & 7;
        qf[((((b * 4 + cpt) * 4 + ks2) * 64) + lg * 16 + lr) * 8 + j] = (_Float16)0.f;
      }
    }
  } else {
    // Wkf[mt][ks][lane][j]: d = mt*16 + (l&15), f = ks*32 + (l>>4)*8 + j
#pragma unroll
    for (int ii = 0; ii < 16; ++ii) {
      const int fl = t + 256 * ii;               // 4096 fragment-lanes
      const int mt = fl >> 9, ks = (fl >> 6) & 7, l = fl & 63;
      const int d = mt * 16 + (l & 15), f0 = ks * 32 + ((l >> 4) << 3);
      H8 h;
#pragma unroll
      for (int j = 0; j < 8; ++j) h.h[j] = (_Float16)Wk[d * FDIM + f0 + j];
      *reinterpret_cast<uint4*>(Wkf + (size_t)fl * 8) = h.q;
    }
  }
}

// ---------------- kernel A: wmax only (read assp, write 1 float/pixel) ----------------
// R8 split: R3 structure minus output phase, minus X retention (K overlays dead X, R4
// layout). LDS 17KB -> ~8 blocks/CU. Writes 1MB total; pure read-dominated.
#define XB_OFF 0        // _Float16 X[32 pix][256 f], XOR-swizzled rows (16384 B) — dead after GEMM1
#define KB_OFF 0        // _Float16 K[32][128] swizzled (8192 B), overlays X after post-GEMM1 barrier
#define SIM_OFF 8192    // float sim[32][65] (8320 B)
#define BKS_OFF 16512   // float bk[128] (512 B)
#define SMEM_BYTES 17024

__global__ __launch_bounds__(256) void wmax_kernel(
    const float* __restrict__ assp, const float* __restrict__ bk,
    const _Float16* __restrict__ Wkf, const _Float16* __restrict__ qf,
    float* __restrict__ wmaxg)
{
  __shared__ __align__(16) char smem[SMEM_BYTES];
  const int t = threadIdx.x;
  const int b = blockIdx.x >> 9;
  const int tile = blockIdx.x & 511;
  const int pix = t & 31, cg = t >> 5;          // staging role: 8 channel-groups of 32
  const int w = t >> 6, l = t & 63, l4 = l >> 4, lr = l & 15;  // MFMA role
  const size_t gbase = (size_t)b * FDIM * HW + (size_t)tile * 32 + pix;

  if (t < 128) ((float*)(smem + BKS_OFF))[t] = bk[t];

  // ---- stage: load 32 f32 assp values, convert to f16 into LDS (transposed, swizzled) ----
#pragma unroll
  for (int g = 0; g < 4; ++g) {
    float x[8];
#pragma unroll
    for (int j = 0; j < 8; ++j) x[j] = assp[gbase + (size_t)(cg * 32 + g * 8 + j) * HW];
    H8 h;
#pragma unroll
    for (int j = 0; j < 8; ++j) h.h[j] = (_Float16)x[j];
    const int colb = (cg * 32 + g * 8) * 2;
    *reinterpret_cast<uint4*>(smem + XB_OFF + pix * 512 + (colb ^ ((pix & 7) << 4))) = h.q;
  }
  __syncthreads();

  // ---- GEMM1: key[d in w*32..+32][32 pix] = Wk x X ----
  f32x4 acc[2][2];
#pragma unroll
  for (int mt = 0; mt < 2; ++mt)
#pragma unroll
    for (int nt = 0; nt < 2; ++nt) acc[mt][nt] = (f32x4){0.f, 0.f, 0.f, 0.f};

#pragma unroll
  for (int ks = 0; ks < 8; ++ks) {
    const half8 a0 = *reinterpret_cast<const half8*>(Wkf + ((size_t)((w * 2 + 0) * 8 + ks) * 64 + l) * 8);
    const half8 a1 = *reinterpret_cast<const half8*>(Wkf + ((size_t)((w * 2 + 1) * 8 + ks) * 64 + l) * 8);
#pragma unroll
    for (int nt = 0; nt < 2; ++nt) {
      const int row = nt * 16 + lr;
      const half8 bb = *reinterpret_cast<const half8*>(
          smem + XB_OFF + row * 512 + ((ks * 64 + l4 * 16) ^ ((row & 7) << 4)));
      acc[0][nt] = __builtin_amdgcn_mfma_f32_16x16x32_f16(a0, bb, acc[0][nt], 0, 0, 0);
      acc[1][nt] = __builtin_amdgcn_mfma_f32_16x16x32_f16(a1, bb, acc[1][nt], 0, 0, 0);
    }
  }
  __syncthreads();   // all waves done reading X; K may overlay it

  // ---- +bk, f16-ify, K tile to LDS: K[pix][d] (overlays dead X) ----
  const float* bks = (const float*)(smem + BKS_OFF);
#pragma unroll
  for (int mt = 0; mt < 2; ++mt) {
    const int d0 = w * 32 + mt * 16 + l4 * 4;   // D rows: m = (l>>4)*4 + reg
    const float b0 = bks[d0], b1 = bks[d0 + 1], b2 = bks[d0 + 2], b3 = bks[d0 + 3];
#pragma unroll
    for (int nt = 0; nt < 2; ++nt) {
      H4 h;
      h.h[0] = (_Float16)(acc[mt][nt][0] + b0);
      h.h[1] = (_Float16)(acc[mt][nt][1] + b1);
      h.h[2] = (_Float16)(acc[mt][nt][2] + b2);
      h.h[3] = (_Float16)(acc[mt][nt][3] + b3);
      const int prow = nt * 16 + lr;            // D cols: n = l&15
      *reinterpret_cast<uint2*>(smem + KB_OFF + prow * 256 + ((d0 * 2) ^ ((prow & 7) << 4))) = h.q;
    }
  }
  __syncthreads();

  // ---- GEMM2: sim[cp tile w][32 pix] = q x key ----
  f32x4 acc2[2];
#pragma unroll
  for (int nt = 0; nt < 2; ++nt) acc2[nt] = (f32x4){0.f, 0.f, 0.f, 0.f};
#pragma unroll
  for (int ks2 = 0; ks2 < 4; ++ks2) {
    const half8 a2 = *reinterpret_cast<const half8*>(qf + ((size_t)((b * 4 + w) * 4 + ks2) * 64 + l) * 8);
#pragma unroll
    for (int nt = 0; nt < 2; ++nt) {
      const int row = nt * 16 + lr;
      const half8 bb = *reinterpret_cast<const half8*>(
          smem + KB_OFF + row * 256 + ((ks2 * 64 + l4 * 16) ^ ((row & 7) << 4)));
      acc2[nt] = __builtin_amdgcn_mfma_f32_16x16x32_f16(a2, bb, acc2[nt], 0, 0, 0);
    }
  }
  // sim region [8192,16512) is disjoint from K [0,8192): no barrier needed

  // ---- scatter sim[pix][cp] (f32, stride 65) ----
  float* sim = (float*)(smem + SIM_OFF);
#pragma unroll
  for (int nt = 0; nt < 2; ++nt) {
    const int spix = nt * 16 + lr;
#pragma unroll
    for (int r = 0; r < 4; ++r) sim[spix * 65 + (w * 16 + l4 * 4 + r)] = acc2[nt][r];
  }
  __syncthreads();

  // ---- wmax[pix] = 1 / sum_cp exp(sim - max); cp < 60 real; direct global write ----
  if (t < 128) {
    const int spix = t >> 2, rq = t & 3;        // 4 threads per pixel, 15 cps each
    const float* srow = sim + spix * 65 + rq * 15;
    float m = -1e30f;
#pragma unroll
    for (int i = 0; i < 15; ++i) m = fmaxf(m, srow[i]);
    m = fmaxf(m, __shfl_xor(m, 1));
    m = fmaxf(m, __shfl_xor(m, 2));
    float s = 0.f;
#pragma unroll
    for (int i = 0; i < 15; ++i) s += expf(srow[i] - m);
    s += __shfl_xor(s, 1);
    s += __shfl_xor(s, 2);
    if (rq == 0) wmaxg[(size_t)b * HW + tile * 32 + spix] = 1.0f / s;
  }
}

// ---------------- kernel B: out = assp * wmax — pure linear float4 stream ----------------
__global__ __launch_bounds__(256) void mul_kernel(
    const f32x4* __restrict__ in, const f32x4* __restrict__ wm4,
    f32x4* __restrict__ outv)
{
  const long long base = (long long)blockIdx.x * 256 + threadIdx.x;
#pragma unroll 1
  for (int it = 0; it < 32; ++it) {
    const long long v = base + (long long)it * (2048LL * 256);
    const long long bb = v >> 20;                 // batch (2^20 float4 per batch)
    const f32x4 a = in[v];
    const f32x4 wv = wm4[(bb << 12) + (v & 4095)];
    const f32x4 r = a * wv;
    __builtin_nontemporal_store(r, &outv[v]);
  }
}

extern "C" void kernel_launch(void* const* d_in, const int* in_sizes, int n_in,
                              void* d_out, int out_size, void* d_ws, size_t ws_size,
                              hipStream_t stream) {
  const float* assp  = (const float*)d_in[0];
  const float* proto = (const float*)d_in[1];
  const float* Wk    = (const float*)d_in[2];
  const float* bk    = (const float*)d_in[3];
  const float* Wq    = (const float*)d_in[4];
  const float* bq    = (const float*)d_in[5];
  float* out = (float*)d_out;
  float* protos_out = out + (size_t)16 * FDIM * HW;   // 67,108,864

  _Float16* Wkf = (_Float16*)d_ws;                    // 32768 halves (64 KB)
  _Float16* qf  = Wkf + 32768;                        // 131072 halves (256 KB)
  float* wmaxg  = (float*)(qf + 131072);              // 16*16384 floats (1 MB)

  prep_kernel<<<97, 256, 0, stream>>>(proto, Wk, Wq, bq, protos_out, Wkf, qf);
  wmax_kernel<<<16 * 512, 256, 0, stream>>>(assp, bk, Wkf, qf, wmaxg);
  mul_kernel<<<2048, 256, 0, stream>>>((const f32x4*)assp, (const f32x4*)wmaxg,
                                       (f32x4*)out);
}

// Round 10
// 152.284 us; speedup vs baseline: 1.2112x; 1.2112x over previous
//
#include <hip/hip_runtime.h>

typedef _Float16 half8 __attribute__((ext_vector_type(8)));
typedef float f32x4 __attribute__((ext_vector_type(4)));

#define HW 16384
#define FDIM 256
#define DDIM 128

union H8 { half8 v; uint4 q; _Float16 h[8]; };

// ---------------- prep1: q projection (f32, exact) -> protos_out ----------------
__global__ __launch_bounds__(256) void prep_kernel(
    const float* __restrict__ proto, const float* __restrict__ Wq,
    const float* __restrict__ bq, float* __restrict__ protos_out)
{
  const int bid = blockIdx.x, t = threadIdx.x;
  const int b = bid / 6, c = bid % 6;
  __shared__ float protoS[10 * FDIM];
  const float* pbase = proto + (size_t)((b * 6 + c) * 10) * FDIM;
#pragma unroll
  for (int i = 0; i < 10; ++i) protoS[t + 256 * i] = pbase[t + 256 * i];
  __syncthreads();
#pragma unroll
  for (int i = 0; i < 5; ++i) {
    const int oid = t + 256 * i;               // 1280 outputs: (p, d)
    const int p = oid >> 7, d = oid & 127;
    const float* wq = Wq + (size_t)(c * DDIM + d) * FDIM;
    float acc = bq[c * DDIM + d];
    for (int f = 0; f < FDIM; ++f) acc += wq[f] * protoS[p * FDIM + f];
    protos_out[((b * 6 + c) * 10 + p) * DDIM + d] = acc;
  }
}

// ---------------- prep2: Wc = q . Wk (A-fragment layout) + qbk = q . bk ----------------
// Wc[b][cp][f] = sum_d q[b,cp,d] * Wk[d,f]; written as MFMA A-fragments:
// Wcf[b][cpt][ks][lane][j]: cp = cpt*16 + (l&15), f = ks*32 + (l>>4)*8 + j
__global__ __launch_bounds__(256) void prep2_kernel(
    const float* __restrict__ q /* = protos_out [B][60][128] */,
    const float* __restrict__ Wk, const float* __restrict__ bk,
    _Float16* __restrict__ Wcf, float* __restrict__ qbk)
{
  __shared__ float qS[16][128];
  __shared__ float bkS[128];
  const int t = threadIdx.x;
  const int b = blockIdx.x >> 2, cpt = blockIdx.x & 3;
#pragma unroll
  for (int i = 0; i < 8; ++i) {
    const int idx = t + 256 * i;               // 0..2047
    const int row = idx >> 7, d = idx & 127;
    const int cp = cpt * 16 + row;
    qS[row][d] = (cp < 60) ? q[((size_t)b * 60 + cp) * DDIM + d] : 0.f;
  }
  if (t < 128) bkS[t] = bk[t];
  __syncthreads();

  float acc[16];
#pragma unroll
  for (int i = 0; i < 16; ++i) acc[i] = 0.f;
  const int f = t;                             // one f-column per thread
  for (int d = 0; d < 128; ++d) {
    const float wv = Wk[d * FDIM + f];         // coalesced; broadcast qS reads
#pragma unroll
    for (int i = 0; i < 16; ++i) acc[i] += qS[i][d] * wv;
  }
  const int ks = f >> 5, lg = (f >> 3) & 3, j = f & 7;
#pragma unroll
  for (int i = 0; i < 16; ++i)
    Wcf[((((size_t)(b * 4 + cpt) * 8 + ks) * 64) + lg * 16 + i) * 8 + j] = (_Float16)acc[i];

  if (t < 16) {
    float s = 0.f;
    for (int d = 0; d < 128; ++d) s += qS[t][d] * bkS[d];
    qbk[b * 64 + cpt * 16 + t] = s;
  }
}

// ---------------- fused: ONE GEMM (Wc x X) -> softmax-max -> weighted assp ----------------
// R10: sim = Wc.x + qbk collapses GEMM1+bias+Kwrite+GEMM2 into one K=256 GEMM.
// Phases: stage -> bar -> GEMM+scatter -> bar -> softmax -> bar -> output. 3 barriers (R3: 5).
#define XB_OFF 0        // _Float16 X[32 pix][256 f], XOR-swizzled rows (16384 B) — alive to end
#define SIM_OFF 16384   // float sim[32][65] (8320 B)
#define QBK_OFF 24704   // float qbk[64] (256 B)
#define WM_OFF 24960    // float wmax[32] (128 B)
#define SMEM_BYTES 25088

__global__ __launch_bounds__(256) void fused_kernel(
    const float* __restrict__ assp, const _Float16* __restrict__ Wcf,
    const float* __restrict__ qbk, float* __restrict__ out)
{
  __shared__ __align__(16) char smem[SMEM_BYTES];
  const int t = threadIdx.x;
  const int b = blockIdx.x >> 9;
  const int tile = blockIdx.x & 511;
  const int pix = t & 31, cg = t >> 5;          // staging role: 8 channel-groups of 32
  const int w = t >> 6, l = t & 63, l4 = l >> 4, lr = l & 15;  // MFMA role: wave w = cp-tile w
  const size_t gbase = (size_t)b * FDIM * HW + (size_t)tile * 32 + pix;

  if (t < 64) ((float*)(smem + QBK_OFF))[t] = qbk[b * 64 + t];

  // ---- stage: load 32 f32 assp values, convert to f16 into LDS (transposed, swizzled) ----
#pragma unroll
  for (int g = 0; g < 4; ++g) {
    float x[8];
#pragma unroll
    for (int j = 0; j < 8; ++j) x[j] = assp[gbase + (size_t)(cg * 32 + g * 8 + j) * HW];
    H8 h;
#pragma unroll
    for (int j = 0; j < 8; ++j) h.h[j] = (_Float16)x[j];
    const int colb = (cg * 32 + g * 8) * 2;
    *reinterpret_cast<uint4*>(smem + XB_OFF + pix * 512 + (colb ^ ((pix & 7) << 4))) = h.q;
  }
  __syncthreads();

  // ---- GEMM: sim[cp in w*16..+16][32 pix] = Wc x X  (K = 256) ----
  f32x4 acc2[2];
#pragma unroll
  for (int nt = 0; nt < 2; ++nt) acc2[nt] = (f32x4){0.f, 0.f, 0.f, 0.f};
#pragma unroll
  for (int ks = 0; ks < 8; ++ks) {
    const half8 a2 = *reinterpret_cast<const half8*>(Wcf + ((size_t)((b * 4 + w) * 8 + ks) * 64 + l) * 8);
#pragma unroll
    for (int nt = 0; nt < 2; ++nt) {
      const int row = nt * 16 + lr;
      const half8 bb = *reinterpret_cast<const half8*>(
          smem + XB_OFF + row * 512 + ((ks * 64 + l4 * 16) ^ ((row & 7) << 4)));
      acc2[nt] = __builtin_amdgcn_mfma_f32_16x16x32_f16(a2, bb, acc2[nt], 0, 0, 0);
    }
  }

  // ---- scatter sim[pix][cp] + qbk (f32, stride 65; disjoint from live X) ----
  float* sim = (float*)(smem + SIM_OFF);
  const float* qbkS = (const float*)(smem + QBK_OFF);
#pragma unroll
  for (int nt = 0; nt < 2; ++nt) {
    const int spix = nt * 16 + lr;
#pragma unroll
    for (int r = 0; r < 4; ++r)
      sim[spix * 65 + (w * 16 + l4 * 4 + r)] = acc2[nt][r] + qbkS[w * 16 + l4 * 4 + r];
  }
  __syncthreads();

  // ---- wmax[pix] = 1 / sum_cp exp(sim - max); cp < 60 real ----
  if (t < 128) {
    const int spix = t >> 2, rq = t & 3;        // 4 threads per pixel, 15 cps each
    const float* srow = sim + spix * 65 + rq * 15;
    float m = -1e30f;
#pragma unroll
    for (int i = 0; i < 15; ++i) m = fmaxf(m, srow[i]);
    m = fmaxf(m, __shfl_xor(m, 1));
    m = fmaxf(m, __shfl_xor(m, 2));
    float s = 0.f;
#pragma unroll
    for (int i = 0; i < 15; ++i) s += expf(srow[i] - m);
    s += __shfl_xor(s, 1);
    s += __shfl_xor(s, 2);
    if (rq == 0) ((float*)(smem + WM_OFF))[spix] = 1.0f / s;
  }
  __syncthreads();

  // ---- output: read back own f16 X from LDS, multiply by wmax, nontemporal f32 store ----
  const float wm = ((float*)(smem + WM_OFF))[pix];
#pragma unroll
  for (int g = 0; g < 4; ++g) {
    H8 h;
    const int colb = (cg * 32 + g * 8) * 2;
    h.q = *reinterpret_cast<const uint4*>(smem + XB_OFF + pix * 512 + (colb ^ ((pix & 7) << 4)));
#pragma unroll
    for (int j = 0; j < 8; ++j)
      __builtin_nontemporal_store((float)h.h[j] * wm,
                                  &out[gbase + (size_t)(cg * 32 + g * 8 + j) * HW]);
  }
}

extern "C" void kernel_launch(void* const* d_in, const int* in_sizes, int n_in,
                              void* d_out, int out_size, void* d_ws, size_t ws_size,
                              hipStream_t stream) {
  const float* assp  = (const float*)d_in[0];
  const float* proto = (const float*)d_in[1];
  const float* Wk    = (const float*)d_in[2];
  const float* bk    = (const float*)d_in[3];
  const float* Wq    = (const float*)d_in[4];
  const float* bq    = (const float*)d_in[5];
  float* out = (float*)d_out;
  float* protos_out = out + (size_t)16 * FDIM * HW;   // 67,108,864

  _Float16* Wcf = (_Float16*)d_ws;                    // 16*4*8*64*8 = 262144 halves (512 KB)
  float* qbk    = (float*)(Wcf + 262144);             // 16*64 floats (4 KB)

  prep_kernel<<<96, 256, 0, stream>>>(proto, Wq, bq, protos_out);
  prep2_kernel<<<64, 256, 0, stream>>>(protos_out, Wk, bk, Wcf, qbk);
  fused_kernel<<<16 * 512, 256, 0, stream>>>(assp, Wcf, qbk, out);
}

// Round 11
// 150.228 us; speedup vs baseline: 1.2278x; 1.0137x over previous
//
#include <hip/hip_runtime.h>

typedef _Float16 half8 __attribute__((ext_vector_type(8)));
typedef float f32x4 __attribute__((ext_vector_type(4)));

#define HW 16384
#define FDIM 256
#define DDIM 128
// swizzle byte-bits 4-6 with px bits 0-2 ^ 3-5: read-frag diversity AND write diversity
#define SWZ(p) ((((p) & 7) ^ (((p) >> 3) & 7)) << 4)

union H8 { half8 v; uint4 q; _Float16 h[8]; };

// ---------------- prep1: q projection (f32, exact) -> protos_out ----------------
__global__ __launch_bounds__(256) void prep_kernel(
    const float* __restrict__ proto, const float* __restrict__ Wq,
    const float* __restrict__ bq, float* __restrict__ protos_out)
{
  const int bid = blockIdx.x, t = threadIdx.x;
  const int b = bid / 6, c = bid % 6;
  __shared__ float protoS[10 * FDIM];
  const float* pbase = proto + (size_t)((b * 6 + c) * 10) * FDIM;
#pragma unroll
  for (int i = 0; i < 10; ++i) protoS[t + 256 * i] = pbase[t + 256 * i];
  __syncthreads();
#pragma unroll
  for (int i = 0; i < 5; ++i) {
    const int oid = t + 256 * i;               // 1280 outputs: (p, d)
    const int p = oid >> 7, d = oid & 127;
    const float* wq = Wq + (size_t)(c * DDIM + d) * FDIM;
    float acc = bq[c * DDIM + d];
    for (int f = 0; f < FDIM; ++f) acc += wq[f] * protoS[p * FDIM + f];
    protos_out[((b * 6 + c) * 10 + p) * DDIM + d] = acc;
  }
}

// ---------------- prep2: Wc = q . Wk (A-fragment layout) + qbk = q . bk ----------------
// Wcf[b][cpt][ks][lane][j]: cp = cpt*16 + (l&15), f = ks*32 + (l>>4)*8 + j
__global__ __launch_bounds__(256) void prep2_kernel(
    const float* __restrict__ q /* = protos_out [B][60][128] */,
    const float* __restrict__ Wk, const float* __restrict__ bk,
    _Float16* __restrict__ Wcf, float* __restrict__ qbk)
{
  __shared__ float qS[16][128];
  __shared__ float bkS[128];
  const int t = threadIdx.x;
  const int b = blockIdx.x >> 2, cpt = blockIdx.x & 3;
#pragma unroll
  for (int i = 0; i < 8; ++i) {
    const int idx = t + 256 * i;               // 0..2047
    const int row = idx >> 7, d = idx & 127;
    const int cp = cpt * 16 + row;
    qS[row][d] = (cp < 60) ? q[((size_t)b * 60 + cp) * DDIM + d] : 0.f;
  }
  if (t < 128) bkS[t] = bk[t];
  __syncthreads();

  float acc[16];
#pragma unroll
  for (int i = 0; i < 16; ++i) acc[i] = 0.f;
  const int f = t;                             // one f-column per thread
  for (int d = 0; d < 128; ++d) {
    const float wv = Wk[d * FDIM + f];         // coalesced; broadcast qS reads
#pragma unroll
    for (int i = 0; i < 16; ++i) acc[i] += qS[i][d] * wv;
  }
  const int ks = f >> 5, lg = (f >> 3) & 3, j = f & 7;
#pragma unroll
  for (int i = 0; i < 16; ++i)
    Wcf[((((size_t)(b * 4 + cpt) * 8 + ks) * 64) + lg * 16 + i) * 8 + j] = (_Float16)acc[i];

  if (t < 16) {
    float s = 0.f;
    for (int d = 0; d < 128; ++d) s += qS[t][d] * bkS[d];
    qbk[b * 64 + cpt * 16 + t] = s;
  }
}

// ---------------- fused: 128-px tile, 512B DRAM bursts, one GEMM, regs-retained output ----
// R11: all prior rounds pinned at ~2.4 TB/s with 128B strided chunks (DRAM row thrash).
// 128-px tile -> 512B contiguous per channel on read AND write. xv[16] f32x4 retained in
// registers start-to-end (R1-proven liveness pattern, no loop-carried prefetch -> no spill).
#define WM_OFF 33280    // float wmax[128], after sim[128][65] (33280 B); both overlay dead X
#define SMEM_BYTES 65536 // _Float16 X[128 px][256 f] swizzled = exactly 64 KB

__global__ __launch_bounds__(512) void fused_kernel(
    const float* __restrict__ assp, const _Float16* __restrict__ Wcf,
    const float* __restrict__ qbk, float* __restrict__ out)
{
  __shared__ __align__(16) char smem[SMEM_BYTES];
  const int t = threadIdx.x;
  const int b = blockIdx.x >> 7;               // 16 batches
  const int tile = blockIdx.x & 127;           // 128 tiles of 128 px
  const int l = t & 63, w = t >> 6, l4 = l >> 4, lr = l & 15;
  const int q = t & 31, h = (t >> 5) & 1;      // staging: lane-half h, px-quad q

  const f32x4* in4 = (const f32x4*)assp;
  f32x4* out4 = (f32x4*)out;
  const size_t cbase = (size_t)b * 256;

  // ---- stage: 16 float4 loads/thread (each wave-instr = 2 channels x 512B contiguous);
  //      xv retained to the end for the exact-f32 output multiply ----
  f32x4 xv[16];
#pragma unroll
  for (int i = 0; i < 16; ++i) {
    const int c = w * 32 + i * 2 + h;
    xv[i] = in4[((cbase + c) << 12) + tile * 32 + q];
  }
  // f16 copy into LDS X[px][f], swizzled (write ~4-way banks, read-frag ~2-way)
#pragma unroll
  for (int i = 0; i < 16; ++i) {
    const int c = w * 32 + i * 2 + h;
#pragma unroll
    for (int j = 0; j < 4; ++j) {
      const int px = q * 4 + j;
      *reinterpret_cast<_Float16*>(smem + ((px * 512 + c * 2) ^ SWZ(px))) = (_Float16)xv[i][j];
    }
  }
  __syncthreads();

  // ---- GEMM: sim[cp in cpt*16..+16][px in ph*64..+64] = Wc x X (K=256) ----
  const int cpt = w >> 1, ph = w & 1;
  f32x4 acc[4];
#pragma unroll
  for (int nt = 0; nt < 4; ++nt) acc[nt] = (f32x4){0.f, 0.f, 0.f, 0.f};
#pragma unroll
  for (int ks = 0; ks < 8; ++ks) {
    const half8 a2 = *reinterpret_cast<const half8*>(Wcf + ((size_t)((b * 4 + cpt) * 8 + ks) * 64 + l) * 8);
#pragma unroll
    for (int nt = 0; nt < 4; ++nt) {
      const int px = ph * 64 + nt * 16 + lr;
      const half8 bb = *reinterpret_cast<const half8*>(
          smem + ((px * 512 + ks * 64 + l4 * 16) ^ SWZ(px)));
      acc[nt] = __builtin_amdgcn_mfma_f32_16x16x32_f16(a2, bb, acc[nt], 0, 0, 0);
    }
  }

  // per-lane qbk row (4 consecutive cp, aligned float4; L2-hot 4KB)
  const f32x4 qb = *reinterpret_cast<const f32x4*>(qbk + b * 64 + cpt * 16 + l4 * 4);
  __syncthreads();   // all X reads done; sim may overlay

  // ---- scatter sim[px][cp] (f32, stride 65; overlays dead X) ----
  float* sim = (float*)smem;
#pragma unroll
  for (int nt = 0; nt < 4; ++nt) {
    const int px = ph * 64 + nt * 16 + lr;
#pragma unroll
    for (int r = 0; r < 4; ++r)
      sim[px * 65 + cpt * 16 + l4 * 4 + r] = acc[nt][r] + qb[r];
  }
  __syncthreads();

  // ---- wmax[px] = 1 / sum_cp exp(sim - max); 4 threads/px, cp < 60 real ----
  {
    const int px = t >> 2, rq = t & 3;
    const float* srow = sim + px * 65 + rq * 15;
    float m = -1e30f;
#pragma unroll
    for (int i = 0; i < 15; ++i) m = fmaxf(m, srow[i]);
    m = fmaxf(m, __shfl_xor(m, 1));
    m = fmaxf(m, __shfl_xor(m, 2));
    float s = 0.f;
#pragma unroll
    for (int i = 0; i < 15; ++i) s += expf(srow[i] - m);
    s += __shfl_xor(s, 1);
    s += __shfl_xor(s, 2);
    if (rq == 0) ((float*)(smem + WM_OFF))[px] = 1.0f / s;
  }
  __syncthreads();

  // ---- output: exact f32 xv (regs) * wmax, nontemporal float4 stores (512B bursts) ----
  const f32x4 wmv = *reinterpret_cast<const f32x4*>(smem + WM_OFF + q * 16);
#pragma unroll
  for (int i = 0; i < 16; ++i) {
    const int c = w * 32 + i * 2 + h;
    __builtin_nontemporal_store(xv[i] * wmv, &out4[((cbase + c) << 12) + tile * 32 + q]);
  }
}

extern "C" void kernel_launch(void* const* d_in, const int* in_sizes, int n_in,
                              void* d_out, int out_size, void* d_ws, size_t ws_size,
                              hipStream_t stream) {
  const float* assp  = (const float*)d_in[0];
  const float* proto = (const float*)d_in[1];
  const float* Wk    = (const float*)d_in[2];
  const float* bk    = (const float*)d_in[3];
  const float* Wq    = (const float*)d_in[4];
  const float* bq    = (const float*)d_in[5];
  float* out = (float*)d_out;
  float* protos_out = out + (size_t)16 * FDIM * HW;   // 67,108,864

  _Float16* Wcf = (_Float16*)d_ws;                    // 16*4*8*64*8 = 262144 halves (512 KB)
  float* qbk    = (float*)(Wcf + 262144);             // 16*64 floats (4 KB)

  prep_kernel<<<96, 256, 0, stream>>>(proto, Wq, bq, protos_out);
  prep2_kernel<<<64, 256, 0, stream>>>(protos_out, Wk, bk, Wcf, qbk);
  fused_kernel<<<16 * 128, 512, 0, stream>>>(assp, Wcf, qbk, out);
}